// Round 3
// baseline (907.097 us; speedup 1.0000x reference)
//
#include <hip/hip_runtime.h>
#include <math.h>

#define Vn 5
#define Cn 32
#define Hn 384
#define Wn 384
#define Dn 4
#define Gn 8
#define HWn (Hn*Wn)   // 147456

// ---------- small 3x3 helpers (device) ----------
__device__ __forceinline__ void inv3(const float* m, float* o){
    float a=m[0],b=m[1],c=m[2],d=m[3],e=m[4],f=m[5],g=m[6],h=m[7],i=m[8];
    float A =  e*i - f*h;
    float B = -(d*i - f*g);
    float C =  d*h - e*g;
    float det = a*A + b*B + c*C;
    float r = 1.f/det;
    o[0] = A*r;            o[1] = -(b*i - c*h)*r;  o[2] =  (b*f - c*e)*r;
    o[3] = B*r;            o[4] =  (a*i - c*g)*r;  o[5] = -(a*f - c*d)*r;
    o[6] = C*r;            o[7] = -(a*h - b*g)*r;  o[8] =  (a*e - b*d)*r;
}
__device__ __forceinline__ void mm3(const float* a, const float* b, float* o){
    #pragma unroll
    for (int r=0;r<3;r++)
        #pragma unroll
        for (int c=0;c<3;c++)
            o[r*3+c] = a[r*3+0]*b[0*3+c] + a[r*3+1]*b[1*3+c] + a[r*3+2]*b[2*3+c];
}
__device__ __forceinline__ void mv3(const float* a, const float* v, float* o){
    #pragma unroll
    for (int r=0;r<3;r++)
        o[r] = a[r*3+0]*v[0] + a[r*3+1]*v[1] + a[r*3+2]*v[2];
}

__device__ __forceinline__ unsigned short f2bf(float f){
    unsigned int x = __float_as_uint(f);
    unsigned int r = (x + 0x7fffu + ((x >> 16) & 1u)) >> 16;   // RNE
    return (unsigned short)r;
}

// ---------- transpose+convert source views (C,H,W) fp32 -> (H*W, C) bf16 ----------
__global__ __launch_bounds__(256)
void transpose_kernel(const float* __restrict__ feat, unsigned short* __restrict__ featT){
    __shared__ float tile[32][257];
    const int s  = blockIdx.y;            // 0..3 -> view s+1
    const int p0 = blockIdx.x * 256;      // pixel tile base
    const int t  = threadIdx.x;
    const float* src = feat + (size_t)(s+1)*Cn*HWn + p0;
    #pragma unroll
    for (int k=0;k<8;k++){
        const int i   = k*256 + t;
        const int px4 = (i & 63) * 4;
        const int ch  = i >> 6;
        const float4 v = *(const float4*)(src + (size_t)ch*HWn + px4);
        tile[ch][px4+0]=v.x; tile[ch][px4+1]=v.y; tile[ch][px4+2]=v.z; tile[ch][px4+3]=v.w;
    }
    __syncthreads();
    // each thread packs one pixel's 32 channels -> 16 uints -> 4 uint4 (64 B)
    uint4 o[4];
    unsigned int* ou = (unsigned int*)o;
    #pragma unroll
    for (int c=0;c<16;c++){
        const unsigned int lo = f2bf(tile[2*c  ][t]);
        const unsigned int hi = f2bf(tile[2*c+1][t]);
        ou[c] = lo | (hi << 16);
    }
    uint4* dst = (uint4*)(featT + ((size_t)s*HWn + p0 + t)*Cn);
    dst[0]=o[0]; dst[1]=o[1]; dst[2]=o[2]; dst[3]=o[3];
}

// ---------- fused main kernel: one thread per (pixel, source view) ----------
// Block = 256 threads = 64 pixels x 4 views; 4 view-lanes adjacent -> shfl_xor.
__global__ __launch_bounds__(256, 3)
void gbinet_kernel(const float* __restrict__ feat,
                   const float* __restrict__ depths,
                   const float* __restrict__ Kin,
                   const float* __restrict__ Ein,
                   const float* __restrict__ w0, const float* __restrict__ b0,
                   const float* __restrict__ w1, const float* __restrict__ b1,
                   const float* __restrict__ w2, const float* __restrict__ b2,
                   const unsigned short* __restrict__ featT,
                   float* __restrict__ out)
{
    __shared__ float sW0[128], sW1[128], sB0[16], sB1[8], sW2[8], sB2s[1];
    __shared__ float sM[48];            // per source view: A[9] + c[3]
    __shared__ float sOut[64*33];       // 64 pixels x 32 outputs (pad 33)
    const int t = threadIdx.x;
    if (t < 128){ sW0[t] = w0[t]; sW1[t] = w1[t]; }
    if (t < 16) sB0[t] = b0[t];
    if (t < 8){ sB1[t] = b1[t]; sW2[t] = w2[t]; }
    if (t == 0){
        sB2s[0] = b2[0];
        // fold projection chain: uvd = A_s * (x,y,1) * depth + c_s
        float K0inv[9]; inv3(Kin, K0inv);
        float R0[9], t0[3];
        #pragma unroll
        for (int r=0;r<3;r++){
            #pragma unroll
            for (int c=0;c<3;c++) R0[r*3+c] = Ein[r*4+c];
            t0[r] = Ein[r*4+3];
        }
        float R0inv[9]; inv3(R0, R0inv);
        float M0[9]; mm3(R0inv, K0inv, M0);
        float Rt0[3]; mv3(R0inv, t0, Rt0);
        for (int s=1;s<Vn;s++){
            const float* Ks = Kin + s*9;
            const float* Es = Ein + s*12;
            float Rs[9], ts[3];
            #pragma unroll
            for (int r=0;r<3;r++){
                #pragma unroll
                for (int c=0;c<3;c++) Rs[r*3+c] = Es[r*4+c];
                ts[r] = Es[r*4+3];
            }
            float T1[9]; mm3(Rs, M0, T1);
            float A[9];  mm3(Ks, T1, A);
            float Rr[3]; mv3(Rs, Rt0, Rr);
            float tv[3] = { ts[0]-Rr[0], ts[1]-Rr[1], ts[2]-Rr[2] };
            float cv[3]; mv3(Ks, tv, cv);
            float* dm = &sM[(s-1)*12];
            #pragma unroll
            for (int i=0;i<9;i++) dm[i] = A[i];
            #pragma unroll
            for (int i=0;i<3;i++) dm[9+i] = cv[i];
        }
    }
    __syncthreads();

    const int pixLocal = t >> 2;        // 0..63
    const int s        = t & 3;         // source view index (0..3 -> view s+1)
    const int pix      = blockIdx.x*64 + pixLocal;
    const float xg = (float)(pix % Wn) + 0.5f;
    const float yg = (float)(pix / Wn) + 0.5f;

    float ref[Cn];
    #pragma unroll
    for (int c=0;c<Cn;c++) ref[c] = feat[(size_t)c*HWn + pix];   // view 0, fp32
    float dep[Dn];
    #pragma unroll
    for (int d=0;d<Dn;d++) dep[d] = depths[(size_t)d*HWn + pix];

    const float* M = &sM[s*12];
    const float bx = M[0]*xg + M[1]*yg + M[2];
    const float by = M[3]*xg + M[4]*yg + M[5];
    const float bz = M[6]*xg + M[7]*yg + M[8];
    const float cx = M[9], cy = M[10], cz = M[11];
    const unsigned short* vbase = featT + (size_t)s*HWn*Cn;

    float sim[Gn][Dn];
    #pragma unroll
    for (int d=0;d<Dn;d++){
        const float dd = dep[d];
        const float ux = fmaf(bx, dd, cx);
        const float uy = fmaf(by, dd, cy);
        const float uz = fmaf(bz, dd, cz) + 1e-9f;
        const float rz = 1.f/uz;
        const float px = ux*rz, py = uy*rz;
        const float x0 = floorf(px), y0 = floorf(py);
        const float wx1 = px - x0, wy1 = py - y0;
        const float wx0 = 1.f - wx1, wy0 = 1.f - wy1;
        const bool vx0 = (x0 >= 0.f)      && (x0 <= (float)(Wn-1));
        const bool vx1 = (x0+1.f >= 0.f)  && (x0+1.f <= (float)(Wn-1));
        const bool vy0 = (y0 >= 0.f)      && (y0 <= (float)(Hn-1));
        const bool vy1 = (y0+1.f >= 0.f)  && (y0+1.f <= (float)(Hn-1));
        const float wt[4] = { (vx0&&vy0) ? wx0*wy0 : 0.f,
                              (vx1&&vy0) ? wx1*wy0 : 0.f,
                              (vx0&&vy1) ? wx0*wy1 : 0.f,
                              (vx1&&vy1) ? wx1*wy1 : 0.f };
        // clamped integer coords (always safe to load)
        const int xi0 = (int)fminf(fmaxf(x0,     0.f), (float)(Wn-1));
        const int xi1 = (int)fminf(fmaxf(x0+1.f, 0.f), (float)(Wn-1));
        const int yi0 = (int)fminf(fmaxf(y0,     0.f), (float)(Hn-1));
        const int yi1 = (int)fminf(fmaxf(y0+1.f, 0.f), (float)(Hn-1));
        const int xi[2] = { xi0, xi1 };
        const int yi[2] = { yi0, yi1 };

        // issue all 16 loads (4 taps x 64 B) before consuming
        uint4 dat[4][4];
        #pragma unroll
        for (int tap=0;tap<4;tap++){
            const uint4* p = (const uint4*)(vbase + ((size_t)yi[tap>>1]*Wn + xi[tap&1])*Cn);
            dat[tap][0]=p[0]; dat[tap][1]=p[1]; dat[tap][2]=p[2]; dat[tap][3]=p[3];
        }

        float sg[Gn];
        #pragma unroll
        for (int g=0; g<Gn; g++) sg[g] = 0.f;
        #pragma unroll
        for (int tap=0;tap<4;tap++){
            const float w = wt[tap];
            #pragma unroll
            for (int q=0;q<4;q++){
                const uint4 f = dat[tap][q];
                const unsigned int uu[4] = {f.x, f.y, f.z, f.w};
                #pragma unroll
                for (int j=0;j<2;j++){
                    const int g = 2*q + j;
                    const float d0 = __uint_as_float(uu[2*j]   << 16);
                    const float d1 = __uint_as_float(uu[2*j]   & 0xffff0000u);
                    const float d2 = __uint_as_float(uu[2*j+1] << 16);
                    const float d3 = __uint_as_float(uu[2*j+1] & 0xffff0000u);
                    float dt = d0*ref[g*4+0];
                    dt = fmaf(d1, ref[g*4+1], dt);
                    dt = fmaf(d2, ref[g*4+2], dt);
                    dt = fmaf(d3, ref[g*4+3], dt);
                    sg[g] = fmaf(w, dt, sg[g]);
                }
            }
        }
        #pragma unroll
        for (int g=0; g<Gn; g++) sim[g][d] = sg[g]*0.25f;  // mean over 4 ch/group
    }

    // pixelwise net over 4 depths; max(sigmoid) == sigmoid(max logit)
    float maxlog = -3.0e38f;
    #pragma unroll
    for (int d=0; d<Dn; d++){
        float h[16];
        #pragma unroll
        for (int o=0;o<16;o++){
            float a = sB0[o];
            #pragma unroll
            for (int g=0; g<Gn; g++) a = fmaf(sW0[o*Gn+g], sim[g][d], a);
            h[o] = fmaxf(a, 0.f);
        }
        float lg = sB2s[0];
        #pragma unroll
        for (int o=0;o<8;o++){
            float a = sB1[o];
            #pragma unroll
            for (int i=0;i<16;i++) a = fmaf(sW1[o*16+i], h[i], a);
            lg = fmaf(sW2[o], fmaxf(a, 0.f), lg);
        }
        maxlog = fmaxf(maxlog, lg);
    }
    const float vw = 1.f/(1.f + __expf(-maxlog));

    // scale by vw, butterfly-reduce across the 4 view lanes
    float wsum = vw;
    wsum += __shfl_xor(wsum, 1);
    wsum += __shfl_xor(wsum, 2);
    #pragma unroll
    for (int g=0;g<Gn;g++)
        #pragma unroll
        for (int d=0;d<Dn;d++){
            float v = sim[g][d]*vw;
            v += __shfl_xor(v, 1);
            v += __shfl_xor(v, 2);
            sim[g][d] = v;
        }

    if (s == 0){
        const float invw = 1.f/wsum;
        #pragma unroll
        for (int g=0;g<Gn;g++)
            #pragma unroll
            for (int d=0;d<Dn;d++)
                sOut[pixLocal*33 + g*Dn + d] = sim[g][d]*invw;
    }
    __syncthreads();

    // coalesced write-out: 32 planes x 64 pixels
    float* oBase = out + (size_t)blockIdx.x*64;
    #pragma unroll
    for (int k=0;k<8;k++){
        const int e     = k*256 + t;
        const int plane = e >> 6;
        const int pixel = e & 63;
        oBase[(size_t)plane*HWn + pixel] = sOut[pixel*33 + plane];
    }
}

extern "C" void kernel_launch(void* const* d_in, const int* in_sizes, int n_in,
                              void* d_out, int out_size, void* d_ws, size_t ws_size,
                              hipStream_t stream)
{
    (void)in_sizes; (void)n_in; (void)out_size; (void)ws_size;
    const float* feat   = (const float*)d_in[0];
    const float* depths = (const float*)d_in[1];
    const float* K      = (const float*)d_in[2];
    const float* E      = (const float*)d_in[3];
    const float* w0     = (const float*)d_in[4];
    const float* b0     = (const float*)d_in[5];
    const float* w1     = (const float*)d_in[6];
    const float* b1     = (const float*)d_in[7];
    const float* w2     = (const float*)d_in[8];
    const float* b2     = (const float*)d_in[9];
    float* out = (float*)d_out;
    unsigned short* featT = (unsigned short*)d_ws;   // (V-1, HW, C) bf16 = 37.7 MB

    dim3 g(HWn/256, Vn-1);
    transpose_kernel<<<g, 256, 0, stream>>>(feat, featT);
    gbinet_kernel<<<HWn/64, 256, 0, stream>>>(feat, depths, K, E,
                                              w0,b0,w1,b1,w2,b2, featT, out);
}

// Round 4
// 639.161 us; speedup vs baseline: 1.4192x; 1.4192x over previous
//
#include <hip/hip_runtime.h>
#include <math.h>

#define Vn 5
#define Cn 32
#define Hn 384
#define Wn 384
#define Dn 4
#define Gn 8
#define HWn (Hn*Wn)   // 147456

// ---------- small 3x3 helpers (device) ----------
__device__ __forceinline__ void inv3(const float* m, float* o){
    float a=m[0],b=m[1],c=m[2],d=m[3],e=m[4],f=m[5],g=m[6],h=m[7],i=m[8];
    float A =  e*i - f*h;
    float B = -(d*i - f*g);
    float C =  d*h - e*g;
    float det = a*A + b*B + c*C;
    float r = 1.f/det;
    o[0] = A*r;            o[1] = -(b*i - c*h)*r;  o[2] =  (b*f - c*e)*r;
    o[3] = B*r;            o[4] =  (a*i - c*g)*r;  o[5] = -(a*f - c*d)*r;
    o[6] = C*r;            o[7] = -(a*h - b*g)*r;  o[8] =  (a*e - b*d)*r;
}
__device__ __forceinline__ void mm3(const float* a, const float* b, float* o){
    #pragma unroll
    for (int r=0;r<3;r++)
        #pragma unroll
        for (int c=0;c<3;c++)
            o[r*3+c] = a[r*3+0]*b[0*3+c] + a[r*3+1]*b[1*3+c] + a[r*3+2]*b[2*3+c];
}
__device__ __forceinline__ void mv3(const float* a, const float* v, float* o){
    #pragma unroll
    for (int r=0;r<3;r++)
        o[r] = a[r*3+0]*v[0] + a[r*3+1]*v[1] + a[r*3+2]*v[2];
}

__device__ __forceinline__ unsigned short f2bf(float f){
    unsigned int x = __float_as_uint(f);
    unsigned int r = (x + 0x7fffu + ((x >> 16) & 1u)) >> 16;   // RNE
    return (unsigned short)r;
}

// ---------- transpose+convert source views (C,H,W) fp32 -> (H*W, C) bf16 ----------
__global__ __launch_bounds__(256)
void transpose_kernel(const float* __restrict__ feat, unsigned short* __restrict__ featT){
    __shared__ float tile[32][257];
    const int s  = blockIdx.y;            // 0..3 -> view s+1
    const int p0 = blockIdx.x * 256;      // pixel tile base
    const int t  = threadIdx.x;
    const float* src = feat + (size_t)(s+1)*Cn*HWn + p0;
    #pragma unroll
    for (int k=0;k<8;k++){
        const int i   = k*256 + t;
        const int px4 = (i & 63) * 4;
        const int ch  = i >> 6;
        const float4 v = *(const float4*)(src + (size_t)ch*HWn + px4);
        tile[ch][px4+0]=v.x; tile[ch][px4+1]=v.y; tile[ch][px4+2]=v.z; tile[ch][px4+3]=v.w;
    }
    __syncthreads();
    // each thread packs one pixel's 32 channels -> 16 uints -> 4 uint4 (64 B)
    uint4* dst = (uint4*)(featT + ((size_t)s*HWn + p0 + t)*Cn);
    #pragma unroll
    for (int q=0;q<4;q++){
        uint4 o;
        o.x = (unsigned int)f2bf(tile[8*q+0][t]) | ((unsigned int)f2bf(tile[8*q+1][t]) << 16);
        o.y = (unsigned int)f2bf(tile[8*q+2][t]) | ((unsigned int)f2bf(tile[8*q+3][t]) << 16);
        o.z = (unsigned int)f2bf(tile[8*q+4][t]) | ((unsigned int)f2bf(tile[8*q+5][t]) << 16);
        o.w = (unsigned int)f2bf(tile[8*q+6][t]) | ((unsigned int)f2bf(tile[8*q+7][t]) << 16);
        dst[q] = o;
    }
}

// unpack one uint (2 bf16 ch) and accumulate into group-dot dt
#define CONSUME_PAIR(u0, u1, g)                                            \
    {                                                                      \
        const float d0 = __uint_as_float((u0) << 16);                      \
        const float d1 = __uint_as_float((u0) & 0xffff0000u);              \
        const float d2 = __uint_as_float((u1) << 16);                      \
        const float d3 = __uint_as_float((u1) & 0xffff0000u);              \
        float dt = d0*ref[(g)*4+0];                                        \
        dt = fmaf(d1, ref[(g)*4+1], dt);                                   \
        dt = fmaf(d2, ref[(g)*4+2], dt);                                   \
        dt = fmaf(d3, ref[(g)*4+3], dt);                                   \
        sg[(g)] = fmaf(w, dt, sg[(g)]);                                    \
    }

// bilinear tap: always loads (coords pre-clamped), weight may be 0
__device__ __forceinline__ void tap_bf16(const unsigned short* __restrict__ vbase,
                                         int xc, int yc, float w,
                                         const float* ref, float* sg)
{
    const uint4* p = (const uint4*)(vbase + ((size_t)yc*Wn + xc)*Cn);
    const uint4 q0 = p[0];
    const uint4 q1 = p[1];
    const uint4 q2 = p[2];
    const uint4 q3 = p[3];
    CONSUME_PAIR(q0.x, q0.y, 0)
    CONSUME_PAIR(q0.z, q0.w, 1)
    CONSUME_PAIR(q1.x, q1.y, 2)
    CONSUME_PAIR(q1.z, q1.w, 3)
    CONSUME_PAIR(q2.x, q2.y, 4)
    CONSUME_PAIR(q2.z, q2.w, 5)
    CONSUME_PAIR(q3.x, q3.y, 6)
    CONSUME_PAIR(q3.z, q3.w, 7)
}

// ---------- fused main kernel: one thread per (pixel, source view) ----------
// Block = 256 threads = 64 pixels x 4 views; 4 view-lanes adjacent -> shfl_xor.
__global__ __launch_bounds__(256, 4)
void gbinet_kernel(const float* __restrict__ feat,
                   const float* __restrict__ depths,
                   const float* __restrict__ Kin,
                   const float* __restrict__ Ein,
                   const float* __restrict__ w0, const float* __restrict__ b0,
                   const float* __restrict__ w1, const float* __restrict__ b1,
                   const float* __restrict__ w2, const float* __restrict__ b2,
                   const unsigned short* __restrict__ featT,
                   float* __restrict__ out)
{
    __shared__ float sW0[128], sW1[128], sB0[16], sB1[8], sW2[8], sB2s[1];
    __shared__ float sM[48];            // per source view: A[9] + c[3]
    __shared__ float sOut[64*33];       // 64 pixels x 32 outputs (pad 33)
    const int t = threadIdx.x;
    if (t < 128){ sW0[t] = w0[t]; sW1[t] = w1[t]; }
    if (t < 16) sB0[t] = b0[t];
    if (t < 8){ sB1[t] = b1[t]; sW2[t] = w2[t]; }
    if (t == 0){
        sB2s[0] = b2[0];
        // fold projection chain: uvd = A_s * (x,y,1) * depth + c_s
        float K0inv[9]; inv3(Kin, K0inv);
        float R0[9], t0[3];
        #pragma unroll
        for (int r=0;r<3;r++){
            #pragma unroll
            for (int c=0;c<3;c++) R0[r*3+c] = Ein[r*4+c];
            t0[r] = Ein[r*4+3];
        }
        float R0inv[9]; inv3(R0, R0inv);
        float M0[9]; mm3(R0inv, K0inv, M0);
        float Rt0[3]; mv3(R0inv, t0, Rt0);
        for (int s=1;s<Vn;s++){
            const float* Ks = Kin + s*9;
            const float* Es = Ein + s*12;
            float Rs[9], ts[3];
            #pragma unroll
            for (int r=0;r<3;r++){
                #pragma unroll
                for (int c=0;c<3;c++) Rs[r*3+c] = Es[r*4+c];
                ts[r] = Es[r*4+3];
            }
            float T1[9]; mm3(Rs, M0, T1);
            float A[9];  mm3(Ks, T1, A);
            float Rr[3]; mv3(Rs, Rt0, Rr);
            float tv[3] = { ts[0]-Rr[0], ts[1]-Rr[1], ts[2]-Rr[2] };
            float cv[3]; mv3(Ks, tv, cv);
            float* dm = &sM[(s-1)*12];
            #pragma unroll
            for (int i=0;i<9;i++) dm[i] = A[i];
            #pragma unroll
            for (int i=0;i<3;i++) dm[9+i] = cv[i];
        }
    }
    __syncthreads();

    const int pixLocal = t >> 2;        // 0..63
    const int s        = t & 3;         // source view index (0..3 -> view s+1)
    const int pix      = blockIdx.x*64 + pixLocal;
    const float xg = (float)(pix % Wn) + 0.5f;
    const float yg = (float)(pix / Wn) + 0.5f;

    float ref[Cn];
    #pragma unroll
    for (int c=0;c<Cn;c++) ref[c] = feat[(size_t)c*HWn + pix];   // view 0, fp32
    float dep[Dn];
    #pragma unroll
    for (int d=0;d<Dn;d++) dep[d] = depths[(size_t)d*HWn + pix];

    const float* M = &sM[s*12];
    const float bx = M[0]*xg + M[1]*yg + M[2];
    const float by = M[3]*xg + M[4]*yg + M[5];
    const float bz = M[6]*xg + M[7]*yg + M[8];
    const float cx = M[9], cy = M[10], cz = M[11];
    const unsigned short* vbase = featT + (size_t)s*HWn*Cn;

    float sim[Gn][Dn];
    #pragma unroll
    for (int d=0;d<Dn;d++){
        const float dd = dep[d];
        const float ux = fmaf(bx, dd, cx);
        const float uy = fmaf(by, dd, cy);
        const float uz = fmaf(bz, dd, cz) + 1e-9f;
        const float rz = 1.f/uz;
        const float px = ux*rz, py = uy*rz;
        const float x0 = floorf(px), y0 = floorf(py);
        const float wx1 = px - x0, wy1 = py - y0;
        const float wx0 = 1.f - wx1, wy0 = 1.f - wy1;
        const bool vx0 = (x0 >= 0.f)     && (x0 <= (float)(Wn-1));
        const bool vx1 = (x0 >= -1.f)    && (x0 <= (float)(Wn-2));
        const bool vy0 = (y0 >= 0.f)     && (y0 <= (float)(Hn-1));
        const bool vy1 = (y0 >= -1.f)    && (y0 <= (float)(Hn-2));
        const float w00 = (vx0&&vy0) ? wx0*wy0 : 0.f;
        const float w10 = (vx1&&vy0) ? wx1*wy0 : 0.f;
        const float w01 = (vx0&&vy1) ? wx0*wy1 : 0.f;
        const float w11 = (vx1&&vy1) ? wx1*wy1 : 0.f;
        // clamped integer coords (always safe to load)
        const int xi0 = (int)fminf(fmaxf(x0,     0.f), (float)(Wn-1));
        const int xi1 = (int)fminf(fmaxf(x0+1.f, 0.f), (float)(Wn-1));
        const int yi0 = (int)fminf(fmaxf(y0,     0.f), (float)(Hn-1));
        const int yi1 = (int)fminf(fmaxf(y0+1.f, 0.f), (float)(Hn-1));

        float sg[Gn];
        #pragma unroll
        for (int g=0; g<Gn; g++) sg[g] = 0.f;
        tap_bf16(vbase, xi0, yi0, w00, ref, sg);
        tap_bf16(vbase, xi1, yi0, w10, ref, sg);
        tap_bf16(vbase, xi0, yi1, w01, ref, sg);
        tap_bf16(vbase, xi1, yi1, w11, ref, sg);
        #pragma unroll
        for (int g=0; g<Gn; g++) sim[g][d] = sg[g]*0.25f;  // mean over 4 ch/group
    }

    // pixelwise net over 4 depths; max(sigmoid) == sigmoid(max logit)
    float maxlog = -3.0e38f;
    #pragma unroll
    for (int d=0; d<Dn; d++){
        float h[16];
        #pragma unroll
        for (int o=0;o<16;o++){
            float a = sB0[o];
            #pragma unroll
            for (int g=0; g<Gn; g++) a = fmaf(sW0[o*Gn+g], sim[g][d], a);
            h[o] = fmaxf(a, 0.f);
        }
        float lg = sB2s[0];
        #pragma unroll
        for (int o=0;o<8;o++){
            float a = sB1[o];
            #pragma unroll
            for (int i=0;i<16;i++) a = fmaf(sW1[o*16+i], h[i], a);
            lg = fmaf(sW2[o], fmaxf(a, 0.f), lg);
        }
        maxlog = fmaxf(maxlog, lg);
    }
    const float vw = 1.f/(1.f + __expf(-maxlog));

    // scale by vw, butterfly-reduce across the 4 view lanes
    float wsum = vw;
    wsum += __shfl_xor(wsum, 1);
    wsum += __shfl_xor(wsum, 2);
    #pragma unroll
    for (int g=0;g<Gn;g++)
        #pragma unroll
        for (int d=0;d<Dn;d++){
            float v = sim[g][d]*vw;
            v += __shfl_xor(v, 1);
            v += __shfl_xor(v, 2);
            sim[g][d] = v;
        }

    if (s == 0){
        const float invw = 1.f/wsum;
        #pragma unroll
        for (int g=0;g<Gn;g++)
            #pragma unroll
            for (int d=0;d<Dn;d++)
                sOut[pixLocal*33 + g*Dn + d] = sim[g][d]*invw;
    }
    __syncthreads();

    // coalesced write-out: 32 planes x 64 pixels
    float* oBase = out + (size_t)blockIdx.x*64;
    #pragma unroll
    for (int k=0;k<8;k++){
        const int e     = k*256 + t;
        const int plane = e >> 6;
        const int pixel = e & 63;
        oBase[(size_t)plane*HWn + pixel] = sOut[pixel*33 + plane];
    }
}

extern "C" void kernel_launch(void* const* d_in, const int* in_sizes, int n_in,
                              void* d_out, int out_size, void* d_ws, size_t ws_size,
                              hipStream_t stream)
{
    (void)in_sizes; (void)n_in; (void)out_size; (void)ws_size;
    const float* feat   = (const float*)d_in[0];
    const float* depths = (const float*)d_in[1];
    const float* K      = (const float*)d_in[2];
    const float* E      = (const float*)d_in[3];
    const float* w0     = (const float*)d_in[4];
    const float* b0     = (const float*)d_in[5];
    const float* w1     = (const float*)d_in[6];
    const float* b1     = (const float*)d_in[7];
    const float* w2     = (const float*)d_in[8];
    const float* b2     = (const float*)d_in[9];
    float* out = (float*)d_out;
    unsigned short* featT = (unsigned short*)d_ws;   // (V-1, HW, C) bf16 = 37.7 MB

    dim3 g(HWn/256, Vn-1);
    transpose_kernel<<<g, 256, 0, stream>>>(feat, featT);
    gbinet_kernel<<<HWn/64, 256, 0, stream>>>(feat, depths, K, E,
                                              w0,b0,w1,b1,w2,b2, featT, out);
}

// Round 5
// 253.750 us; speedup vs baseline: 3.5748x; 2.5189x over previous
//
#include <hip/hip_runtime.h>
#include <math.h>

#define Vn 5
#define Cn 32
#define Hn 384
#define Wn 384
#define Dn 4
#define Gn 8
#define HWn (Hn*Wn)   // 147456

// ---------- small 3x3 helpers (device) ----------
__device__ __forceinline__ void inv3(const float* m, float* o){
    float a=m[0],b=m[1],c=m[2],d=m[3],e=m[4],f=m[5],g=m[6],h=m[7],i=m[8];
    float A =  e*i - f*h;
    float B = -(d*i - f*g);
    float C =  d*h - e*g;
    float det = a*A + b*B + c*C;
    float r = 1.f/det;
    o[0] = A*r;            o[1] = -(b*i - c*h)*r;  o[2] =  (b*f - c*e)*r;
    o[3] = B*r;            o[4] =  (a*i - c*g)*r;  o[5] = -(a*f - c*d)*r;
    o[6] = C*r;            o[7] = -(a*h - b*g)*r;  o[8] =  (a*e - b*d)*r;
}
__device__ __forceinline__ void mm3(const float* a, const float* b, float* o){
    #pragma unroll
    for (int r=0;r<3;r++)
        #pragma unroll
        for (int c=0;c<3;c++)
            o[r*3+c] = a[r*3+0]*b[0*3+c] + a[r*3+1]*b[1*3+c] + a[r*3+2]*b[2*3+c];
}
__device__ __forceinline__ void mv3(const float* a, const float* v, float* o){
    #pragma unroll
    for (int r=0;r<3;r++)
        o[r] = a[r*3+0]*v[0] + a[r*3+1]*v[1] + a[r*3+2]*v[2];
}

__device__ __forceinline__ unsigned short f2bf(float f){
    unsigned int x = __float_as_uint(f);
    unsigned int r = (x + 0x7fffu + ((x >> 16) & 1u)) >> 16;   // RNE
    return (unsigned short)r;
}

// ---------- transpose+convert source views (C,H,W) fp32 -> (H*W, C) bf16 ----------
__global__ __launch_bounds__(256)
void transpose_kernel(const float* __restrict__ feat, unsigned short* __restrict__ featT){
    __shared__ float tile[32][257];
    const int s  = blockIdx.y;            // 0..3 -> view s+1
    const int p0 = blockIdx.x * 256;      // pixel tile base
    const int t  = threadIdx.x;
    const float* src = feat + (size_t)(s+1)*Cn*HWn + p0;
    #pragma unroll
    for (int k=0;k<8;k++){
        const int i   = k*256 + t;
        const int px4 = (i & 63) * 4;
        const int ch  = i >> 6;
        const float4 v = *(const float4*)(src + (size_t)ch*HWn + px4);
        tile[ch][px4+0]=v.x; tile[ch][px4+1]=v.y; tile[ch][px4+2]=v.z; tile[ch][px4+3]=v.w;
    }
    __syncthreads();
    // each thread packs one pixel's 32 channels -> 16 uints -> 4 uint4 (64 B)
    uint4* dst = (uint4*)(featT + ((size_t)s*HWn + p0 + t)*Cn);
    #pragma unroll
    for (int q=0;q<4;q++){
        uint4 o;
        o.x = (unsigned int)f2bf(tile[8*q+0][t]) | ((unsigned int)f2bf(tile[8*q+1][t]) << 16);
        o.y = (unsigned int)f2bf(tile[8*q+2][t]) | ((unsigned int)f2bf(tile[8*q+3][t]) << 16);
        o.z = (unsigned int)f2bf(tile[8*q+4][t]) | ((unsigned int)f2bf(tile[8*q+5][t]) << 16);
        o.w = (unsigned int)f2bf(tile[8*q+6][t]) | ((unsigned int)f2bf(tile[8*q+7][t]) << 16);
        dst[q] = o;
    }
}

// unpack one uint (2 bf16 ch) and accumulate into group-dot
#define CONSUME_PAIR(u0, u1, g)                                            \
    {                                                                      \
        const float d0 = __uint_as_float((u0) << 16);                      \
        const float d1 = __uint_as_float((u0) & 0xffff0000u);              \
        const float d2 = __uint_as_float((u1) << 16);                      \
        const float d3 = __uint_as_float((u1) & 0xffff0000u);              \
        float dt = d0*ref[(g)*4+0];                                        \
        dt = fmaf(d1, ref[(g)*4+1], dt);                                   \
        dt = fmaf(d2, ref[(g)*4+2], dt);                                   \
        dt = fmaf(d3, ref[(g)*4+3], dt);                                   \
        sg[(g)] = fmaf(w, dt, sg[(g)]);                                    \
    }

// guarded bilinear tap: loads only if weight nonzero, immediate consume
__device__ __forceinline__ void tap_bf16(const unsigned short* __restrict__ vbase,
                                         int xc, int yc, float w,
                                         const float* ref, float* sg)
{
    if (w != 0.f){
        const uint4* p = (const uint4*)(vbase + ((size_t)yc*Wn + xc)*Cn);
        const uint4 q0 = p[0];
        const uint4 q1 = p[1];
        const uint4 q2 = p[2];
        const uint4 q3 = p[3];
        CONSUME_PAIR(q0.x, q0.y, 0)
        CONSUME_PAIR(q0.z, q0.w, 1)
        CONSUME_PAIR(q1.x, q1.y, 2)
        CONSUME_PAIR(q1.z, q1.w, 3)
        CONSUME_PAIR(q2.x, q2.y, 4)
        CONSUME_PAIR(q2.z, q2.w, 5)
        CONSUME_PAIR(q3.x, q3.y, 6)
        CONSUME_PAIR(q3.z, q3.w, 7)
    }
}

// ---------- fused main kernel: one thread per (pixel, source view) ----------
// Block = 256 threads = 64 pixels x 4 views; 4 view-lanes adjacent -> shfl_xor.
// launch_bounds(256,2): empirical VGPR cap >=128 (cap 64 at arg=4 caused 1.6GB
// of scratch spill traffic in R4 -- this kernel needs ~110 VGPRs).
__global__ __launch_bounds__(256, 2)
void gbinet_kernel(const float* __restrict__ feat,
                   const float* __restrict__ depths,
                   const float* __restrict__ Kin,
                   const float* __restrict__ Ein,
                   const float* __restrict__ w0, const float* __restrict__ b0,
                   const float* __restrict__ w1, const float* __restrict__ b1,
                   const float* __restrict__ w2, const float* __restrict__ b2,
                   const unsigned short* __restrict__ featT,
                   float* __restrict__ out)
{
    __shared__ float sW0[128], sW1[128], sB0[16], sB1[8], sW2[8], sB2s[1];
    __shared__ float sM[48];            // per source view: A[9] + c[3]
    __shared__ float sRef[64*33];       // 64 pixels x 32 ref channels (pad 33)
    __shared__ float sDep[4*65];        // 4 depth planes x 64 pixels (pad 65)
    __shared__ float sOut[64*33];       // 64 pixels x 32 outputs (pad 33)
    const int t = threadIdx.x;
    if (t < 128){ sW0[t] = w0[t]; sW1[t] = w1[t]; }
    if (t < 16) sB0[t] = b0[t];
    if (t < 8){ sB1[t] = b1[t]; sW2[t] = w2[t]; }

    // cooperative coalesced stage of ref (view0 fp32) and depths for 64 pixels
    const int blockBase = blockIdx.x * 64;
    {
        const float* srcR = feat + blockBase;
        #pragma unroll
        for (int k=0;k<8;k++){
            const int i  = k*256 + t;
            const int c  = i >> 6;
            const int px = i & 63;
            sRef[px*33 + c] = srcR[(size_t)c*HWn + px];
        }
        const int dp = t >> 6;          // 0..3
        const int px = t & 63;
        sDep[dp*65 + px] = depths[(size_t)dp*HWn + blockBase + px];
    }

    if (t == 0){
        sB2s[0] = b2[0];
        // fold projection chain: uvd = A_s * (x,y,1) * depth + c_s
        float K0inv[9]; inv3(Kin, K0inv);
        float R0[9], t0[3];
        #pragma unroll
        for (int r=0;r<3;r++){
            #pragma unroll
            for (int c=0;c<3;c++) R0[r*3+c] = Ein[r*4+c];
            t0[r] = Ein[r*4+3];
        }
        float R0inv[9]; inv3(R0, R0inv);
        float M0[9]; mm3(R0inv, K0inv, M0);
        float Rt0[3]; mv3(R0inv, t0, Rt0);
        for (int s=1;s<Vn;s++){
            const float* Ks = Kin + s*9;
            const float* Es = Ein + s*12;
            float Rs[9], ts[3];
            #pragma unroll
            for (int r=0;r<3;r++){
                #pragma unroll
                for (int c=0;c<3;c++) Rs[r*3+c] = Es[r*4+c];
                ts[r] = Es[r*4+3];
            }
            float T1[9]; mm3(Rs, M0, T1);
            float A[9];  mm3(Ks, T1, A);
            float Rr[3]; mv3(Rs, Rt0, Rr);
            float tv[3] = { ts[0]-Rr[0], ts[1]-Rr[1], ts[2]-Rr[2] };
            float cv[3]; mv3(Ks, tv, cv);
            float* dm = &sM[(s-1)*12];
            #pragma unroll
            for (int i=0;i<9;i++) dm[i] = A[i];
            #pragma unroll
            for (int i=0;i<3;i++) dm[9+i] = cv[i];
        }
    }
    __syncthreads();

    const int pixLocal = t >> 2;        // 0..63
    const int s        = t & 3;         // source view index (0..3 -> view s+1)
    const int pix      = blockBase + pixLocal;
    const float xg = (float)(pix % Wn) + 0.5f;
    const float yg = (float)(pix / Wn) + 0.5f;

    float ref[Cn];
    #pragma unroll
    for (int c=0;c<Cn;c++) ref[c] = sRef[pixLocal*33 + c];
    float dep[Dn];
    #pragma unroll
    for (int d=0;d<Dn;d++) dep[d] = sDep[d*65 + pixLocal];

    const float* M = &sM[s*12];
    const float bx = M[0]*xg + M[1]*yg + M[2];
    const float by = M[3]*xg + M[4]*yg + M[5];
    const float bz = M[6]*xg + M[7]*yg + M[8];
    const float cx = M[9], cy = M[10], cz = M[11];
    const unsigned short* vbase = featT + (size_t)s*HWn*Cn;

    float sim[Gn][Dn];
    #pragma unroll
    for (int d=0;d<Dn;d++){
        const float dd = dep[d];
        const float ux = fmaf(bx, dd, cx);
        const float uy = fmaf(by, dd, cy);
        const float uz = fmaf(bz, dd, cz) + 1e-9f;
        const float rz = 1.f/uz;
        const float px = ux*rz, py = uy*rz;
        const float x0 = floorf(px), y0 = floorf(py);
        const float wx1 = px - x0, wy1 = py - y0;
        const float wx0 = 1.f - wx1, wy0 = 1.f - wy1;
        const bool vx0 = (x0 >= 0.f)     && (x0 <= (float)(Wn-1));
        const bool vx1 = (x0 >= -1.f)    && (x0 <= (float)(Wn-2));
        const bool vy0 = (y0 >= 0.f)     && (y0 <= (float)(Hn-1));
        const bool vy1 = (y0 >= -1.f)    && (y0 <= (float)(Hn-2));
        const float w00 = (vx0&&vy0) ? wx0*wy0 : 0.f;
        const float w10 = (vx1&&vy0) ? wx1*wy0 : 0.f;
        const float w01 = (vx0&&vy1) ? wx0*wy1 : 0.f;
        const float w11 = (vx1&&vy1) ? wx1*wy1 : 0.f;
        // clamped integer coords (always safe to load)
        const int xi0 = (int)fminf(fmaxf(x0,     0.f), (float)(Wn-1));
        const int xi1 = (int)fminf(fmaxf(x0+1.f, 0.f), (float)(Wn-1));
        const int yi0 = (int)fminf(fmaxf(y0,     0.f), (float)(Hn-1));
        const int yi1 = (int)fminf(fmaxf(y0+1.f, 0.f), (float)(Hn-1));

        float sg[Gn];
        #pragma unroll
        for (int g=0; g<Gn; g++) sg[g] = 0.f;
        tap_bf16(vbase, xi0, yi0, w00, ref, sg);
        tap_bf16(vbase, xi1, yi0, w10, ref, sg);
        tap_bf16(vbase, xi0, yi1, w01, ref, sg);
        tap_bf16(vbase, xi1, yi1, w11, ref, sg);
        #pragma unroll
        for (int g=0; g<Gn; g++) sim[g][d] = sg[g]*0.25f;  // mean over 4 ch/group
    }

    // pixelwise net over 4 depths; max(sigmoid) == sigmoid(max logit)
    float maxlog = -3.0e38f;
    #pragma unroll
    for (int d=0; d<Dn; d++){
        float h[16];
        #pragma unroll
        for (int o=0;o<16;o++){
            float a = sB0[o];
            #pragma unroll
            for (int g=0; g<Gn; g++) a = fmaf(sW0[o*Gn+g], sim[g][d], a);
            h[o] = fmaxf(a, 0.f);
        }
        float lg = sB2s[0];
        #pragma unroll
        for (int o=0;o<8;o++){
            float a = sB1[o];
            #pragma unroll
            for (int i=0;i<16;i++) a = fmaf(sW1[o*16+i], h[i], a);
            lg = fmaf(sW2[o], fmaxf(a, 0.f), lg);
        }
        maxlog = fmaxf(maxlog, lg);
    }
    const float vw = 1.f/(1.f + __expf(-maxlog));

    // scale by vw, butterfly-reduce across the 4 view lanes
    float wsum = vw;
    wsum += __shfl_xor(wsum, 1);
    wsum += __shfl_xor(wsum, 2);
    #pragma unroll
    for (int g=0;g<Gn;g++)
        #pragma unroll
        for (int d=0;d<Dn;d++){
            float v = sim[g][d]*vw;
            v += __shfl_xor(v, 1);
            v += __shfl_xor(v, 2);
            sim[g][d] = v;
        }

    if (s == 0){
        const float invw = 1.f/wsum;
        #pragma unroll
        for (int g=0;g<Gn;g++)
            #pragma unroll
            for (int d=0;d<Dn;d++)
                sOut[pixLocal*33 + g*Dn + d] = sim[g][d]*invw;
    }
    __syncthreads();

    // coalesced write-out: 32 planes x 64 pixels
    float* oBase = out + blockBase;
    #pragma unroll
    for (int k=0;k<8;k++){
        const int e     = k*256 + t;
        const int plane = e >> 6;
        const int pixel = e & 63;
        oBase[(size_t)plane*HWn + pixel] = sOut[pixel*33 + plane];
    }
}

extern "C" void kernel_launch(void* const* d_in, const int* in_sizes, int n_in,
                              void* d_out, int out_size, void* d_ws, size_t ws_size,
                              hipStream_t stream)
{
    (void)in_sizes; (void)n_in; (void)out_size; (void)ws_size;
    const float* feat   = (const float*)d_in[0];
    const float* depths = (const float*)d_in[1];
    const float* K      = (const float*)d_in[2];
    const float* E      = (const float*)d_in[3];
    const float* w0     = (const float*)d_in[4];
    const float* b0     = (const float*)d_in[5];
    const float* w1     = (const float*)d_in[6];
    const float* b1     = (const float*)d_in[7];
    const float* w2     = (const float*)d_in[8];
    const float* b2     = (const float*)d_in[9];
    float* out = (float*)d_out;
    unsigned short* featT = (unsigned short*)d_ws;   // (V-1, HW, C) bf16 = 37.7 MB

    dim3 g(HWn/256, Vn-1);
    transpose_kernel<<<g, 256, 0, stream>>>(feat, featT);
    gbinet_kernel<<<HWn/64, 256, 0, stream>>>(feat, depths, K, E,
                                              w0,b0,w1,b1,w2,b2, featT, out);
}

// Round 6
// 242.281 us; speedup vs baseline: 3.7440x; 1.0473x over previous
//
#include <hip/hip_runtime.h>
#include <math.h>

#define Vn 5
#define Cn 32
#define Hn 384
#define Wn 384
#define Dn 4
#define Gn 8
#define HWn (Hn*Wn)   // 147456

typedef _Float16 h2 __attribute__((ext_vector_type(2)));

__device__ __forceinline__ float fdot2h(h2 a, h2 b, float c){
#if __has_builtin(__builtin_amdgcn_fdot2)
    return __builtin_amdgcn_fdot2(a, b, c, false);
#else
    return (float)a.x*(float)b.x + (float)a.y*(float)b.y + c;
#endif
}

// ---------- small 3x3 helpers (device) ----------
__device__ __forceinline__ void inv3(const float* m, float* o){
    float a=m[0],b=m[1],c=m[2],d=m[3],e=m[4],f=m[5],g=m[6],h=m[7],i=m[8];
    float A =  e*i - f*h;
    float B = -(d*i - f*g);
    float C =  d*h - e*g;
    float det = a*A + b*B + c*C;
    float r = 1.f/det;
    o[0] = A*r;            o[1] = -(b*i - c*h)*r;  o[2] =  (b*f - c*e)*r;
    o[3] = B*r;            o[4] =  (a*i - c*g)*r;  o[5] = -(a*f - c*d)*r;
    o[6] = C*r;            o[7] = -(a*h - b*g)*r;  o[8] =  (a*e - b*d)*r;
}
__device__ __forceinline__ void mm3(const float* a, const float* b, float* o){
    #pragma unroll
    for (int r=0;r<3;r++)
        #pragma unroll
        for (int c=0;c<3;c++)
            o[r*3+c] = a[r*3+0]*b[0*3+c] + a[r*3+1]*b[1*3+c] + a[r*3+2]*b[2*3+c];
}
__device__ __forceinline__ void mv3(const float* a, const float* v, float* o){
    #pragma unroll
    for (int r=0;r<3;r++)
        o[r] = a[r*3+0]*v[0] + a[r*3+1]*v[1] + a[r*3+2]*v[2];
}

__device__ __forceinline__ unsigned int packh2(float a, float b){
    h2 h;
    h.x = (_Float16)a;
    h.y = (_Float16)b;
    return __builtin_bit_cast(unsigned int, h);
}

// ---------- transpose+convert source views (C,H,W) fp32 -> (H*W, C) f16 ----------
__global__ __launch_bounds__(256)
void transpose_kernel(const float* __restrict__ feat, unsigned short* __restrict__ featT){
    __shared__ float tile[32][257];
    const int s  = blockIdx.y;            // 0..3 -> view s+1
    const int p0 = blockIdx.x * 256;      // pixel tile base
    const int t  = threadIdx.x;
    const float* src = feat + (size_t)(s+1)*Cn*HWn + p0;
    #pragma unroll
    for (int k=0;k<8;k++){
        const int i   = k*256 + t;
        const int px4 = (i & 63) * 4;
        const int ch  = i >> 6;
        const float4 v = *(const float4*)(src + (size_t)ch*HWn + px4);
        tile[ch][px4+0]=v.x; tile[ch][px4+1]=v.y; tile[ch][px4+2]=v.z; tile[ch][px4+3]=v.w;
    }
    __syncthreads();
    // each thread packs one pixel's 32 channels -> 16 uints -> 4 uint4 (64 B)
    uint4* dst = (uint4*)(featT + ((size_t)s*HWn + p0 + t)*Cn);
    #pragma unroll
    for (int q=0;q<4;q++){
        uint4 o;
        o.x = packh2(tile[8*q+0][t], tile[8*q+1][t]);
        o.y = packh2(tile[8*q+2][t], tile[8*q+3][t]);
        o.z = packh2(tile[8*q+4][t], tile[8*q+5][t]);
        o.w = packh2(tile[8*q+6][t], tile[8*q+7][t]);
        dst[q] = o;
    }
}

// one group (4 ch = 2 half2): two v_dot2_f32_f16 + one fma
#define DOTG(uA, uB, g)                                                        \
    {                                                                          \
        const h2 pa = __builtin_bit_cast(h2, (uA));                            \
        const h2 pb = __builtin_bit_cast(h2, (uB));                            \
        const float dt = fdot2h(pa, r2[2*(g)], fdot2h(pb, r2[2*(g)+1], 0.f));  \
        sg[(g)] = fmaf(w, dt, sg[(g)]);                                        \
    }

// guarded bilinear tap: loads only if weight nonzero, immediate consume
__device__ __forceinline__ void tap_f16(const unsigned short* __restrict__ vbase,
                                        int xc, int yc, float w,
                                        const h2* r2, float* sg)
{
    if (w != 0.f){
        const uint4* p = (const uint4*)(vbase + ((size_t)yc*Wn + xc)*Cn);
        const uint4 q0 = p[0];
        const uint4 q1 = p[1];
        const uint4 q2 = p[2];
        const uint4 q3 = p[3];
        DOTG(q0.x, q0.y, 0)
        DOTG(q0.z, q0.w, 1)
        DOTG(q1.x, q1.y, 2)
        DOTG(q1.z, q1.w, 3)
        DOTG(q2.x, q2.y, 4)
        DOTG(q2.z, q2.w, 5)
        DOTG(q3.x, q3.y, 6)
        DOTG(q3.z, q3.w, 7)
    }
}

// ---------- fused main kernel: one thread per (pixel, source view) ----------
// Block = 256 threads = 64 pixels x 4 views; 4 view-lanes adjacent -> shfl_xor.
// launch_bounds(256,2): empirical VGPR cap 128 (cap 64 at arg=4 caused 1.6GB
// of scratch spill traffic in R4 -- this kernel needs ~100 VGPRs).
__global__ __launch_bounds__(256, 2)
void gbinet_kernel(const float* __restrict__ feat,
                   const float* __restrict__ depths,
                   const float* __restrict__ Kin,
                   const float* __restrict__ Ein,
                   const float* __restrict__ w0, const float* __restrict__ b0,
                   const float* __restrict__ w1, const float* __restrict__ b1,
                   const float* __restrict__ w2, const float* __restrict__ b2,
                   const unsigned short* __restrict__ featT,
                   float* __restrict__ out)
{
    __shared__ float sW0[128], sW1[128], sB0[16], sB1[8], sW2[8], sB2s[1];
    __shared__ float sM[48];            // per source view: A[9] + c[3]
    __shared__ float sRef[64*33];       // 64 pixels x 32 ref channels (pad 33)
    __shared__ float sDep[4*65];        // 4 depth planes x 64 pixels (pad 65)
    __shared__ float sOut[64*33];       // 64 pixels x 32 outputs (pad 33)
    const int t = threadIdx.x;
    if (t < 128){ sW0[t] = w0[t]; sW1[t] = w1[t]; }
    if (t < 16) sB0[t] = b0[t];
    if (t < 8){ sB1[t] = b1[t]; sW2[t] = w2[t]; }

    // cooperative coalesced stage of ref (view0 fp32) and depths for 64 pixels
    const int blockBase = blockIdx.x * 64;
    {
        const float* srcR = feat + blockBase;
        #pragma unroll
        for (int k=0;k<8;k++){
            const int i  = k*256 + t;
            const int c  = i >> 6;
            const int px = i & 63;
            sRef[px*33 + c] = srcR[(size_t)c*HWn + px];
        }
        const int dp = t >> 6;          // 0..3
        const int px = t & 63;
        sDep[dp*65 + px] = depths[(size_t)dp*HWn + blockBase + px];
    }

    if (t == 0){
        sB2s[0] = b2[0];
        // fold projection chain: uvd = A_s * (x,y,1) * depth + c_s
        float K0inv[9]; inv3(Kin, K0inv);
        float R0[9], t0[3];
        #pragma unroll
        for (int r=0;r<3;r++){
            #pragma unroll
            for (int c=0;c<3;c++) R0[r*3+c] = Ein[r*4+c];
            t0[r] = Ein[r*4+3];
        }
        float R0inv[9]; inv3(R0, R0inv);
        float M0[9]; mm3(R0inv, K0inv, M0);
        float Rt0[3]; mv3(R0inv, t0, Rt0);
        for (int s=1;s<Vn;s++){
            const float* Ks = Kin + s*9;
            const float* Es = Ein + s*12;
            float Rs[9], ts[3];
            #pragma unroll
            for (int r=0;r<3;r++){
                #pragma unroll
                for (int c=0;c<3;c++) Rs[r*3+c] = Es[r*4+c];
                ts[r] = Es[r*4+3];
            }
            float T1[9]; mm3(Rs, M0, T1);
            float A[9];  mm3(Ks, T1, A);
            float Rr[3]; mv3(Rs, Rt0, Rr);
            float tv[3] = { ts[0]-Rr[0], ts[1]-Rr[1], ts[2]-Rr[2] };
            float cv[3]; mv3(Ks, tv, cv);
            float* dm = &sM[(s-1)*12];
            #pragma unroll
            for (int i=0;i<9;i++) dm[i] = A[i];
            #pragma unroll
            for (int i=0;i<3;i++) dm[9+i] = cv[i];
        }
    }
    __syncthreads();

    const int pixLocal = t >> 2;        // 0..63
    const int s        = t & 3;         // source view index (0..3 -> view s+1)
    const int pix      = blockBase + pixLocal;
    const float xg = (float)(pix % Wn) + 0.5f;
    const float yg = (float)(pix / Wn) + 0.5f;

    // ref as 16 packed half2 (f16 precision > bf16 for N(0,1) data)
    h2 r2[16];
    #pragma unroll
    for (int k=0;k<16;k++){
        r2[k].x = (_Float16)sRef[pixLocal*33 + 2*k];
        r2[k].y = (_Float16)sRef[pixLocal*33 + 2*k+1];
    }
    float dep[Dn];
    #pragma unroll
    for (int d=0;d<Dn;d++) dep[d] = sDep[d*65 + pixLocal];

    const float* M = &sM[s*12];
    const float bx = M[0]*xg + M[1]*yg + M[2];
    const float by = M[3]*xg + M[4]*yg + M[5];
    const float bz = M[6]*xg + M[7]*yg + M[8];
    const float cx = M[9], cy = M[10], cz = M[11];
    const unsigned short* vbase = featT + (size_t)s*HWn*Cn;

    float sim[Gn][Dn];
    #pragma unroll
    for (int d=0;d<Dn;d++){
        const float dd = dep[d];
        const float ux = fmaf(bx, dd, cx);
        const float uy = fmaf(by, dd, cy);
        const float uz = fmaf(bz, dd, cz) + 1e-9f;
        const float rz = 1.f/uz;
        const float px = ux*rz, py = uy*rz;
        const float x0 = floorf(px), y0 = floorf(py);
        const float wx1 = px - x0, wy1 = py - y0;
        const float wx0 = 1.f - wx1, wy0 = 1.f - wy1;
        const bool vx0 = (x0 >= 0.f)     && (x0 <= (float)(Wn-1));
        const bool vx1 = (x0 >= -1.f)    && (x0 <= (float)(Wn-2));
        const bool vy0 = (y0 >= 0.f)     && (y0 <= (float)(Hn-1));
        const bool vy1 = (y0 >= -1.f)    && (y0 <= (float)(Hn-2));
        // fold the 1/4 group-mean into the tap weights
        const float w00 = (vx0&&vy0) ? 0.25f*wx0*wy0 : 0.f;
        const float w10 = (vx1&&vy0) ? 0.25f*wx1*wy0 : 0.f;
        const float w01 = (vx0&&vy1) ? 0.25f*wx0*wy1 : 0.f;
        const float w11 = (vx1&&vy1) ? 0.25f*wx1*wy1 : 0.f;
        // clamped integer coords (always safe to load)
        const int xi0 = (int)fminf(fmaxf(x0,     0.f), (float)(Wn-1));
        const int xi1 = (int)fminf(fmaxf(x0+1.f, 0.f), (float)(Wn-1));
        const int yi0 = (int)fminf(fmaxf(y0,     0.f), (float)(Hn-1));
        const int yi1 = (int)fminf(fmaxf(y0+1.f, 0.f), (float)(Hn-1));

        float sg[Gn];
        #pragma unroll
        for (int g=0; g<Gn; g++) sg[g] = 0.f;
        tap_f16(vbase, xi0, yi0, w00, r2, sg);
        tap_f16(vbase, xi1, yi0, w10, r2, sg);
        tap_f16(vbase, xi0, yi1, w01, r2, sg);
        tap_f16(vbase, xi1, yi1, w11, r2, sg);
        #pragma unroll
        for (int g=0; g<Gn; g++) sim[g][d] = sg[g];
    }

    // pixelwise net over 4 depths, two depths at a time (v_pk_fma_f32 pairs);
    // max(sigmoid) == sigmoid(max logit)
    float maxlog = -3.0e38f;
    #pragma unroll
    for (int dp=0; dp<2; dp++){
        const int d0 = 2*dp, d1 = 2*dp+1;
        float hx[16], hy[16];
        #pragma unroll
        for (int o=0;o<16;o++){
            float ax = sB0[o], ay = sB0[o];
            #pragma unroll
            for (int g=0; g<Gn; g++){
                const float wv = sW0[o*Gn+g];
                ax = fmaf(wv, sim[g][d0], ax);
                ay = fmaf(wv, sim[g][d1], ay);
            }
            hx[o] = fmaxf(ax, 0.f);
            hy[o] = fmaxf(ay, 0.f);
        }
        float lgx = sB2s[0], lgy = sB2s[0];
        #pragma unroll
        for (int o=0;o<8;o++){
            float ax = sB1[o], ay = sB1[o];
            #pragma unroll
            for (int i=0;i<16;i++){
                const float wv = sW1[o*16+i];
                ax = fmaf(wv, hx[i], ax);
                ay = fmaf(wv, hy[i], ay);
            }
            const float w2v = sW2[o];
            lgx = fmaf(w2v, fmaxf(ax, 0.f), lgx);
            lgy = fmaf(w2v, fmaxf(ay, 0.f), lgy);
        }
        maxlog = fmaxf(maxlog, fmaxf(lgx, lgy));
    }
    const float vw = 1.f/(1.f + __expf(-maxlog));

    // scale by vw, butterfly-reduce across the 4 view lanes
    float wsum = vw;
    wsum += __shfl_xor(wsum, 1);
    wsum += __shfl_xor(wsum, 2);
    #pragma unroll
    for (int g=0;g<Gn;g++)
        #pragma unroll
        for (int d=0;d<Dn;d++){
            float v = sim[g][d]*vw;
            v += __shfl_xor(v, 1);
            v += __shfl_xor(v, 2);
            sim[g][d] = v;
        }

    if (s == 0){
        const float invw = 1.f/wsum;
        #pragma unroll
        for (int g=0;g<Gn;g++)
            #pragma unroll
            for (int d=0;d<Dn;d++)
                sOut[pixLocal*33 + g*Dn + d] = sim[g][d]*invw;
    }
    __syncthreads();

    // coalesced write-out: 32 planes x 64 pixels
    float* oBase = out + blockBase;
    #pragma unroll
    for (int k=0;k<8;k++){
        const int e     = k*256 + t;
        const int plane = e >> 6;
        const int pixel = e & 63;
        oBase[(size_t)plane*HWn + pixel] = sOut[pixel*33 + plane];
    }
}

extern "C" void kernel_launch(void* const* d_in, const int* in_sizes, int n_in,
                              void* d_out, int out_size, void* d_ws, size_t ws_size,
                              hipStream_t stream)
{
    (void)in_sizes; (void)n_in; (void)out_size; (void)ws_size;
    const float* feat   = (const float*)d_in[0];
    const float* depths = (const float*)d_in[1];
    const float* K      = (const float*)d_in[2];
    const float* E      = (const float*)d_in[3];
    const float* w0     = (const float*)d_in[4];
    const float* b0     = (const float*)d_in[5];
    const float* w1     = (const float*)d_in[6];
    const float* b1     = (const float*)d_in[7];
    const float* w2     = (const float*)d_in[8];
    const float* b2     = (const float*)d_in[9];
    float* out = (float*)d_out;
    unsigned short* featT = (unsigned short*)d_ws;   // (V-1, HW, C) f16 = 37.7 MB

    dim3 g(HWn/256, Vn-1);
    transpose_kernel<<<g, 256, 0, stream>>>(feat, featT);
    gbinet_kernel<<<HWn/64, 256, 0, stream>>>(feat, depths, K, E,
                                              w0,b0,w1,b1,w2,b2, featT, out);
}